// Round 17
// baseline (177.767 us; speedup 1.0000x reference)
//
#include <hip/hip_runtime.h>
#include <math.h>

// ---------------------------------------------------------------------------
// 2-layer GAT encoder. CSR-by-dst gather aggregation (atomic-free).
// Round-17 change:
//  * csr_ex stored bf16 (ushort4, 8 B/edge instead of float4 16 B):
//    halves k3's scatter payload and k45's chunk-preload bytes. Attention
//    weights in bf16 add ~0.2% rel error on alpha (threshold headroom 5x).
// ---------------------------------------------------------------------------

typedef __attribute__((ext_vector_type(8))) short s8v;   // 8 bf16 (4 VGPRs)
typedef __attribute__((ext_vector_type(4))) float f4v;   // 4 fp32 acc

__device__ __forceinline__ float leaky02(float x) { return x > 0.f ? x : 0.2f * x; }
__device__ __forceinline__ float eluf(float x) { return x > 0.f ? x : expm1f(x); }
__device__ __forceinline__ unsigned short f2bf(float f) {
    unsigned u = __float_as_uint(f);
    u += 0x7FFFu + ((u >> 16) & 1u);
    return (unsigned short)(u >> 16);
}
__device__ __forceinline__ float bf2f(unsigned short h) {
    return __uint_as_float((unsigned)h << 16);
}

// ---------------- CSR construction + prep + layer-1 scores ----------------

__global__ void k_deg_prep(const int* __restrict__ dst, int* __restrict__ deg,
                           int* __restrict__ rank, int e_cnt,
                           const float* __restrict__ x, const float* __restrict__ W1,
                           const float* __restrict__ W2,
                           const float* __restrict__ attS, const float* __restrict__ attD,
                           unsigned short* __restrict__ xb,
                           unsigned short* __restrict__ w1catT,
                           unsigned short* __restrict__ w2tb,
                           float* __restrict__ a_src1, float* __restrict__ a_dst1,
                           int n16, int n4) {
    __shared__ float wS[64], wD[64];
    int t = threadIdx.x;
    int i = blockIdx.x * 256 + t;
    if (i < 4096) {
        int c = i >> 6, k = i & 63;
        w2tb[c * 64 + k] = f2bf(W2[k * 64 + c]);
        int r = i & 63;                 // r = h*16 + k2
        int h = r >> 4, k2 = r & 15;
        w1catT[c * 64 + r] = f2bf(0.25f * W1[k2 * 256 + h * 64 + c]);
    }
    if (i < n16) xb[i] = f2bf(x[i]);
    if (i < e_cnt) rank[i] = atomicAdd(&deg[dst[i]], 1);
    // layer-1 scores (block-uniform guard so __syncthreads is safe)
    if ((int)blockIdx.x * 256 < n4) {
        if (t < 64) {
            int h = t >> 4, k = t & 15;
            float s = 0.f, d = 0.f;
            for (int c = 0; c < 64; ++c) {
                float w = W1[k * 256 + h * 64 + c];
                s += w * attS[h * 64 + c];
                d += w * attD[h * 64 + c];
            }
            wS[t] = s; wD[t] = d;
        }
        __syncthreads();
        if (i < n4) {
            int n = i >> 2, h = i & 3;
            const float4* xr = (const float4*)(x + (size_t)n * 16);
            const float* ws = wS + h * 16;
            const float* wd = wD + h * 16;
            float s = 0.f, d = 0.f;
#pragma unroll
            for (int q = 0; q < 4; ++q) {
                float4 xv = xr[q];
                s += xv.x * ws[4 * q] + xv.y * ws[4 * q + 1] + xv.z * ws[4 * q + 2] + xv.w * ws[4 * q + 3];
                d += xv.x * wd[4 * q] + xv.y * wd[4 * q + 1] + xv.z * wd[4 * q + 2] + xv.w * wd[4 * q + 3];
            }
            a_src1[i] = s;
            a_dst1[i] = d;
        }
    }
}

__global__ void k_scan_bsums(const int* __restrict__ deg, int* __restrict__ bsum, int n) {
    __shared__ int part[4];
    int i = blockIdx.x * 256 + threadIdx.x;
    int v = (i < n) ? deg[i] : 0;
    int w = v;
#pragma unroll
    for (int off = 32; off; off >>= 1) w += __shfl_xor(w, off, 64);
    if ((threadIdx.x & 63) == 0) part[threadIdx.x >> 6] = w;
    __syncthreads();
    if (threadIdx.x == 0) bsum[blockIdx.x] = part[0] + part[1] + part[2] + part[3];
}

__global__ void k_scan_final(const int* __restrict__ deg, const int* __restrict__ bsum,
                             int* __restrict__ off, int n, int e_cnt, int nb) {
    __shared__ int pre[256];
    __shared__ int s[256];
    int t = threadIdx.x;
    pre[t] = (t < nb && t < (int)blockIdx.x) ? bsum[t] : 0;
    __syncthreads();
#pragma unroll
    for (int d = 128; d; d >>= 1) {
        if (t < d) pre[t] += pre[t + d];
        __syncthreads();
    }
    int bofs = pre[0];
    int i = blockIdx.x * 256 + t;
    int v = (i < n) ? deg[i] : 0;
    s[t] = v;
    __syncthreads();
#pragma unroll
    for (int d = 1; d < 256; d <<= 1) {
        int add = (t >= d) ? s[t - d] : 0;
        __syncthreads();
        s[t] += add;
        __syncthreads();
    }
    int o = bofs + s[t] - v;
    if (i < n) off[i] = o;
    if (i == 0) off[n] = e_cnt;
}

// K3: per-edge exp (4 heads, bf16) + atomic-free scatter into CSR slot.
__global__ void k3_scatter(const int* __restrict__ src, const int* __restrict__ dst,
                           const float* __restrict__ a_src1, const float* __restrict__ a_dst1,
                           const int* __restrict__ off, const int* __restrict__ rank,
                           int* __restrict__ csr_src, ushort4* __restrict__ csr_exb, int e_cnt) {
    int e = blockIdx.x * blockDim.x + threadIdx.x;
    if (e >= e_cnt) return;
    int s = src[e], d = dst[e];
    float4 as = *(const float4*)(a_src1 + (size_t)s * 4);
    float4 ad = *(const float4*)(a_dst1 + (size_t)d * 4);
    ushort4 ex;
    ex.x = f2bf(expf(leaky02(as.x + ad.x)));
    ex.y = f2bf(expf(leaky02(as.y + ad.y)));
    ex.z = f2bf(expf(leaky02(as.z + ad.z)));
    ex.w = f2bf(expf(leaky02(as.w + ad.w)));
    int pos = off[d] + rank[e];
    csr_src[pos] = s;
    csr_exb[pos] = ex;
}

// K45: fused layer-1 aggregation + MLP. Block = 16 nodes.
__global__ void __launch_bounds__(256)
k45_agg_mlp(const int* __restrict__ off, const int* __restrict__ csr_src,
            const ushort4* __restrict__ csr_exb, const unsigned short* __restrict__ xb,
            const float* __restrict__ a_src1, const float* __restrict__ a_dst1,
            const unsigned short* __restrict__ w1catT, const unsigned short* __restrict__ w2tb,
            const float* __restrict__ b1, const float* __restrict__ attS2,
            const float* __restrict__ attD2, unsigned short* __restrict__ h2b,
            float* __restrict__ a_src2, float* __restrict__ a_dst2, int n_nodes) {
    __shared__ unsigned short xaggS[16 * 72];
    __shared__ unsigned short x2s[16 * 72];
    __shared__ int   sS[4][16];
    __shared__ float eS[4][64];   // [edge*4 + head]
    __shared__ float psS[4][16], pdS[4][16];
    const int wave = threadIdx.x >> 6, lane = threadIdx.x & 63;
    const int head = lane >> 4, k = lane & 15;
    const int base = blockIdx.x * 16;
    // ---- phase 1: aggregate raw x for 4 nodes per wave ----
#pragma unroll 1
    for (int r = 0; r < 4; ++r) {
        int n = base + wave * 4 + r;
        float agg = 0.f, den = 1e-16f;
        if (n < n_nodes) {
            int beg = off[n], end = off[n + 1];
            float se = expf(leaky02(a_src1[n * 4 + head] + a_dst1[n * 4 + head]));
            den += se;
            agg = se * bf2f(xb[(size_t)n * 16 + k]);
            for (int cb = beg; cb < end; cb += 16) {
                int m = end - cb; if (m > 16) m = 16;
                if (lane < m) {
                    sS[wave][lane] = csr_src[cb + lane];
                    ushort4 q = csr_exb[cb + lane];
                    float4 qf;
                    qf.x = bf2f(q.x); qf.y = bf2f(q.y);
                    qf.z = bf2f(q.z); qf.w = bf2f(q.w);
                    ((float4*)eS[wave])[lane] = qf;
                }
                int i = 0;
                for (; i + 8 <= m; i += 8) {
                    int s0 = sS[wave][i];     float e0 = eS[wave][4 * i + head];
                    int s1 = sS[wave][i + 1]; float e1 = eS[wave][4 * (i + 1) + head];
                    int s2 = sS[wave][i + 2]; float e2 = eS[wave][4 * (i + 2) + head];
                    int s3 = sS[wave][i + 3]; float e3 = eS[wave][4 * (i + 3) + head];
                    int s4 = sS[wave][i + 4]; float e4 = eS[wave][4 * (i + 4) + head];
                    int s5 = sS[wave][i + 5]; float e5 = eS[wave][4 * (i + 5) + head];
                    int s6 = sS[wave][i + 6]; float e6 = eS[wave][4 * (i + 6) + head];
                    int s7 = sS[wave][i + 7]; float e7 = eS[wave][4 * (i + 7) + head];
                    float v0 = bf2f(xb[(size_t)s0 * 16 + k]);
                    float v1 = bf2f(xb[(size_t)s1 * 16 + k]);
                    float v2 = bf2f(xb[(size_t)s2 * 16 + k]);
                    float v3 = bf2f(xb[(size_t)s3 * 16 + k]);
                    float v4 = bf2f(xb[(size_t)s4 * 16 + k]);
                    float v5 = bf2f(xb[(size_t)s5 * 16 + k]);
                    float v6 = bf2f(xb[(size_t)s6 * 16 + k]);
                    float v7 = bf2f(xb[(size_t)s7 * 16 + k]);
                    agg += e0 * v0 + e1 * v1 + e2 * v2 + e3 * v3
                         + e4 * v4 + e5 * v5 + e6 * v6 + e7 * v7;
                    den += e0 + e1 + e2 + e3 + e4 + e5 + e6 + e7;
                }
                for (; i < m; ++i) {
                    int s = sS[wave][i];
                    float eh = eS[wave][4 * i + head];
                    agg += eh * bf2f(xb[(size_t)s * 16 + k]);
                    den += eh;
                }
            }
        }
        xaggS[(wave * 4 + r) * 72 + lane] = f2bf(agg / den);
    }
    __syncthreads();
    // ---- phase 2: MFMA MLP ----
    const int quad = lane >> 4, l16 = lane & 15;
    const int c = wave * 16 + l16;
    const s8v a0 = *(const s8v*)(xaggS + l16 * 72 + quad * 8);
    const s8v a1f = *(const s8v*)(xaggS + l16 * 72 + 32 + quad * 8);
    const s8v c0 = *(const s8v*)(w1catT + c * 64 + quad * 8);
    const s8v c1 = *(const s8v*)(w1catT + c * 64 + 32 + quad * 8);
    f4v acc = {0.f, 0.f, 0.f, 0.f};
    acc = __builtin_amdgcn_mfma_f32_16x16x32_bf16(a0, c0, acc, 0, 0, 0);
    acc = __builtin_amdgcn_mfma_f32_16x16x32_bf16(a1f, c1, acc, 0, 0, 0);
    float b1c = b1[c];
#pragma unroll
    for (int r = 0; r < 4; ++r)
        x2s[(quad * 4 + r) * 72 + c] = f2bf(eluf(acc[r] + b1c));
    __syncthreads();
    const s8v b0 = *(const s8v*)(w2tb + c * 64 + quad * 8);
    const s8v b1v = *(const s8v*)(w2tb + c * 64 + 32 + quad * 8);
    const s8v a2_0 = *(const s8v*)(x2s + l16 * 72 + quad * 8);
    const s8v a2_1 = *(const s8v*)(x2s + l16 * 72 + 32 + quad * 8);
    f4v acc2 = {0.f, 0.f, 0.f, 0.f};
    acc2 = __builtin_amdgcn_mfma_f32_16x16x32_bf16(a2_0, b0, acc2, 0, 0, 0);
    acc2 = __builtin_amdgcn_mfma_f32_16x16x32_bf16(a2_1, b1v, acc2, 0, 0, 0);
    const float attS_c = attS2[c], attD_c = attD2[c];
    float pS[4], pD[4];
#pragma unroll
    for (int r = 0; r < 4; ++r) {
        int node = base + quad * 4 + r;
        if (node < n_nodes) h2b[(size_t)node * 64 + c] = f2bf(acc2[r]);
        pS[r] = acc2[r] * attS_c;
        pD[r] = acc2[r] * attD_c;
    }
#pragma unroll
    for (int mask = 1; mask < 16; mask <<= 1) {
#pragma unroll
        for (int r = 0; r < 4; ++r) {
            pS[r] += __shfl_xor(pS[r], mask, 64);
            pD[r] += __shfl_xor(pD[r], mask, 64);
        }
    }
    if (l16 == 0) {
#pragma unroll
        for (int r = 0; r < 4; ++r) {
            psS[wave][quad * 4 + r] = pS[r];
            pdS[wave][quad * 4 + r] = pD[r];
        }
    }
    __syncthreads();
    if (threadIdx.x < 16) {
        int node = base + threadIdx.x;
        if (node < n_nodes) {
            a_src2[node] = psS[0][threadIdx.x] + psS[1][threadIdx.x] +
                           psS[2][threadIdx.x] + psS[3][threadIdx.x];
            a_dst2[node] = pdS[0][threadIdx.x] + pdS[1][threadIdx.x] +
                           pdS[2][threadIdx.x] + pdS[3][threadIdx.x];
        }
    }
}

// ---------------- Layer 2 ----------------

// K8: layer-2 softmax-gather, 4 edge-groups x 16 lanes (ushort4 gathers).
__global__ void __launch_bounds__(256, 6)
k8_agg2(const int* __restrict__ off, const int* __restrict__ csr_src,
        const unsigned short* __restrict__ h2b,
        const float* __restrict__ a_src2, const float* __restrict__ a_dst2,
        const float* __restrict__ b2, float* __restrict__ out, int n_nodes) {
    __shared__ int   sS[4][64];
    __shared__ float eS[4][64];
    const int wave = threadIdx.x >> 6, lane = threadIdx.x & 63;
    const int g = lane >> 4, l16 = lane & 15;
    const float4 b2v = ((const float4*)b2)[l16];
    for (int n = blockIdx.x * 4 + wave; n < n_nodes; n += gridDim.x * 4) {
        int beg = off[n], end = off[n + 1];
        float adn = a_dst2[n];
        float se = expf(leaky02(a_src2[n] + adn));
        ushort4 qs = ((const ushort4*)(h2b + (size_t)n * 64))[l16];
        float w0 = (g == 0) ? se : 0.f;   // self term only in group 0
        float a0 = w0 * bf2f(qs.x), a1 = w0 * bf2f(qs.y);
        float a2 = w0 * bf2f(qs.z), a3 = w0 * bf2f(qs.w);
        float den = w0;
        for (int base = beg; base < end; base += 64) {
            int m = end - base; if (m > 64) m = 64;
            if (lane < m) {
                int s = csr_src[base + lane];
                sS[wave][lane] = s;
                eS[wave][lane] = expf(leaky02(a_src2[s] + adn));
            }
            int i = g;
            for (; i + 12 < m; i += 16) {
                int s0 = sS[wave][i];
                int s1 = sS[wave][i + 4];
                int s2 = sS[wave][i + 8];
                int s3 = sS[wave][i + 12];
                ushort4 q0 = ((const ushort4*)(h2b + (size_t)s0 * 64))[l16];
                ushort4 q1 = ((const ushort4*)(h2b + (size_t)s1 * 64))[l16];
                ushort4 q2 = ((const ushort4*)(h2b + (size_t)s2 * 64))[l16];
                ushort4 q3 = ((const ushort4*)(h2b + (size_t)s3 * 64))[l16];
                float e0 = eS[wave][i];
                float e1 = eS[wave][i + 4];
                float e2 = eS[wave][i + 8];
                float e3 = eS[wave][i + 12];
                a0 += e0 * bf2f(q0.x) + e1 * bf2f(q1.x) + e2 * bf2f(q2.x) + e3 * bf2f(q3.x);
                a1 += e0 * bf2f(q0.y) + e1 * bf2f(q1.y) + e2 * bf2f(q2.y) + e3 * bf2f(q3.y);
                a2 += e0 * bf2f(q0.z) + e1 * bf2f(q1.z) + e2 * bf2f(q2.z) + e3 * bf2f(q3.z);
                a3 += e0 * bf2f(q0.w) + e1 * bf2f(q1.w) + e2 * bf2f(q2.w) + e3 * bf2f(q3.w);
                den += e0 + e1 + e2 + e3;
            }
            for (; i < m; i += 4) {
                int s = sS[wave][i];
                float eh = eS[wave][i];
                ushort4 q = ((const ushort4*)(h2b + (size_t)s * 64))[l16];
                a0 += eh * bf2f(q.x); a1 += eh * bf2f(q.y);
                a2 += eh * bf2f(q.z); a3 += eh * bf2f(q.w);
                den += eh;
            }
        }
        a0 += __shfl_xor(a0, 16, 64); a0 += __shfl_xor(a0, 32, 64);
        a1 += __shfl_xor(a1, 16, 64); a1 += __shfl_xor(a1, 32, 64);
        a2 += __shfl_xor(a2, 16, 64); a2 += __shfl_xor(a2, 32, 64);
        a3 += __shfl_xor(a3, 16, 64); a3 += __shfl_xor(a3, 32, 64);
        den += __shfl_xor(den, 16, 64); den += __shfl_xor(den, 32, 64);
        if (lane < 16) {
            float inv = 1.f / (den + 1e-16f);
            float4 ov;
            ov.x = eluf(a0 * inv + b2v.x);
            ov.y = eluf(a1 * inv + b2v.y);
            ov.z = eluf(a2 * inv + b2v.z);
            ov.w = eluf(a3 * inv + b2v.w);
            ((float4*)(out + (size_t)n * 64))[l16] = ov;
        }
    }
}

extern "C" void kernel_launch(void* const* d_in, const int* in_sizes, int n_in,
                              void* d_out, int out_size, void* d_ws, size_t ws_size,
                              hipStream_t stream) {
    const float* x   = (const float*)d_in[0];
    const int*   ei  = (const int*)d_in[1];
    const float* W1  = (const float*)d_in[2];
    const float* as1 = (const float*)d_in[3];
    const float* ad1 = (const float*)d_in[4];
    const float* b1  = (const float*)d_in[5];
    const float* W2  = (const float*)d_in[6];
    const float* as2 = (const float*)d_in[7];
    const float* ad2 = (const float*)d_in[8];
    const float* b2  = (const float*)d_in[9];
    float* out = (float*)d_out;

    const int n = in_sizes[0] / 16;   // 50000
    const int e = in_sizes[1] / 2;    // 400000
    const int* src = ei;
    const int* dst = ei + e;
    const int nb = (n + 255) / 256;   // 196

    float* ws = (float*)d_ws;
    size_t o = 0;
    ushort4* csr_exb = (ushort4*)(ws + o); o += (size_t)e * 2;               // [E,4] bf16
    unsigned short* xb    = (unsigned short*)(ws + o); o += (size_t)n * 8;   // [N,16] bf16
    unsigned short* w2tb   = (unsigned short*)(ws + o); o += 2048;           // [64,64] bf16
    unsigned short* w1catT = (unsigned short*)(ws + o); o += 2048;           // [64,64] bf16
    float*  a_src1  = ws + o; o += (size_t)n * 4;
    float*  a_dst1  = ws + o; o += (size_t)n * 4;
    unsigned short* h2b = (unsigned short*)(ws + o); o += (size_t)n * 32;    // [N,64] bf16
    float*  a_src2  = ws + o; o += (size_t)n;
    float*  a_dst2  = ws + o; o += (size_t)n;
    int*    csr_src = (int*)(ws + o); o += (size_t)e;
    int*    rank    = (int*)(ws + o); o += (size_t)e;
    int*    deg     = (int*)(ws + o); o += (size_t)n;
    int*    off     = (int*)(ws + o); o += (size_t)(n + 4);
    int*    bsum    = (int*)(ws + o); o += 256;

    hipMemsetAsync(deg, 0, (size_t)n * sizeof(int), stream);

    // CSR build + prep + layer-1 scores (covers max(e, n*16) = 800k threads)
    const int prep_threads = (n * 16 > e) ? n * 16 : e;
    k_deg_prep<<<(prep_threads + 255) / 256, 256, 0, stream>>>(
        dst, deg, rank, e, x, W1, W2, as1, ad1, xb, w1catT, w2tb,
        a_src1, a_dst1, n * 16, n * 4);
    k_scan_bsums<<<nb, 256, 0, stream>>>(deg, bsum, n);
    k_scan_final<<<nb, 256, 0, stream>>>(deg, bsum, off, n, e, nb);

    // Layer 1
    k3_scatter<<<(e + 255) / 256, 256, 0, stream>>>(src, dst, a_src1, a_dst1, off, rank,
                                                    csr_src, csr_exb, e);
    k45_agg_mlp<<<(n + 15) / 16, 256, 0, stream>>>(off, csr_src, csr_exb, xb,
                                                   a_src1, a_dst1, w1catT, w2tb, b1,
                                                   as2, ad2, h2b, a_src2, a_dst2, n);

    // Layer 2
    k8_agg2<<<(n + 3) / 4, 256, 0, stream>>>(off, csr_src, h2b, a_src2, a_dst2, b2, out, n);
}